// Round 1
// baseline (833.274 us; speedup 1.0000x reference)
//
#include <hip/hip_runtime.h>
#include <hip/hip_bf16.h>
#include <stdint.h>

#define DIM 128
#define BSTRIDE 136  // padded row stride (bf16 elems) for WkT in LDS: 272 B = 68 dw -> uniform 8-way (minimal) bank pattern for ds_read_b128

typedef float v4f __attribute__((ext_vector_type(4)));
typedef short v8s __attribute__((ext_vector_type(8)));

__device__ __forceinline__ unsigned short f2bf(float f) {
    union { float f; unsigned u; } c; c.f = f;
    unsigned r = c.u + 0x7fffu + ((c.u >> 16) & 1u);
    return (unsigned short)(r >> 16);
}

// ---------------- K0a: qry[b][d] = feat_u[b] @ W_user[:,d] + b_user[d] ----------------
__global__ void qry_kernel(const float* __restrict__ feat_u,
                           const float* __restrict__ W_user,
                           const float* __restrict__ b_user,
                           float* __restrict__ qry) {
    __shared__ float fu[DIM];
    int b = blockIdx.x, t = threadIdx.x;
    fu[t] = feat_u[b * DIM + t];
    __syncthreads();
    float acc = b_user[t];
#pragma unroll 8
    for (int k = 0; k < DIM; ++k) acc += fu[k] * W_user[k * DIM + t];
    qry[b * DIM + t] = acc;
}

// ---------------- K0b: WkT[d][k] (bf16, stride 136) = W_key[k][d] ----------------
__global__ void wkt_kernel(const float* __restrict__ W_key,
                           unsigned short* __restrict__ WkT) {
    int tid = blockIdx.x * blockDim.x + threadIdx.x;  // 16384 threads
    int k = tid >> 7, d = tid & 127;
    WkT[d * BSTRIDE + k] = f2bf(W_key[k * DIM + d]);
}

// ---------------- K1: e[n] = sigmoid(qry[seg[n]] + feat_i[n]@W_key) @ W_e ; store exp(e) ----------------
// block = 256 threads (4 waves). Each wave: 8 strips of 16 nodes; block covers 512 nodes.
__global__ __launch_bounds__(256) void e_kernel(const float* __restrict__ feat_i,
                                                const int* __restrict__ seg,
                                                const unsigned short* __restrict__ WkT,
                                                const float* __restrict__ qry,
                                                const float* __restrict__ W_e,
                                                float* __restrict__ ex_out,
                                                int N) {
    __shared__ __align__(16) unsigned short Blds[DIM * BSTRIDE];  // 34816 B
    __shared__ float We[DIM];
    int t = threadIdx.x;

    // stage WkT -> LDS as float4 chunks (34816 B = 2176 x 16 B)
    {
        const float4* src = (const float4*)WkT;
        float4* dst = (float4*)Blds;
        for (int i = t; i < (DIM * BSTRIDE) / 8; i += 256) dst[i] = src[i];
    }
    if (t < DIM) We[t] = W_e[t];
    __syncthreads();

    const int wave = t >> 6, lane = t & 63;
    const int m = lane & 15, quad = lane >> 4;

    for (int s = 0; s < 8; ++s) {
        const int strip = blockIdx.x * 512 + wave * 128 + s * 16;

        // ---- A fragments: A[m=lane&15][k = kc*32 + quad*8 + j] ----
        v8s a[4];
        const int n_a = strip + m;
        const bool va = (n_a < N);
        const float* arow = feat_i + (size_t)n_a * DIM + quad * 8;
#pragma unroll
        for (int kc = 0; kc < 4; ++kc) {
            float f[8];
            if (va) {
                float4 x0 = *(const float4*)(arow + kc * 32);
                float4 x1 = *(const float4*)(arow + kc * 32 + 4);
                f[0] = x0.x; f[1] = x0.y; f[2] = x0.z; f[3] = x0.w;
                f[4] = x1.x; f[5] = x1.y; f[6] = x1.z; f[7] = x1.w;
            } else {
#pragma unroll
                for (int j = 0; j < 8; ++j) f[j] = 0.f;
            }
            v8s af;
#pragma unroll
            for (int j = 0; j < 8; ++j) af[j] = (short)f2bf(f[j]);
            a[kc] = af;
        }

        // ---- MFMA: 8 col-tiles x 4 K-chunks ----
        v4f acc[8];
#pragma unroll
        for (int c = 0; c < 8; ++c) acc[c] = (v4f){0.f, 0.f, 0.f, 0.f};
#pragma unroll
        for (int c = 0; c < 8; ++c) {
            const unsigned short* brow = Blds + (c * 16 + m) * BSTRIDE + quad * 8;
#pragma unroll
            for (int kc = 0; kc < 4; ++kc) {
                v8s b = *(const v8s*)(brow + kc * 32);
                acc[c] = __builtin_amdgcn_mfma_f32_16x16x32_bf16(a[kc], b, acc[c], 0, 0, 0);
            }
        }

        // ---- epilogue: C row = quad*4 + r, col = c*16 + m ----
#pragma unroll
        for (int r = 0; r < 4; ++r) {
            const int node = strip + quad * 4 + r;
            const bool nv = (node < N);
            const int sg = nv ? seg[node] : 0;
            const float* qrow = qry + sg * DIM;
            float partial = 0.f;
#pragma unroll
            for (int c = 0; c < 8; ++c) {
                const int d = c * 16 + m;
                const float x = acc[c][r] + qrow[d];
                const float sig = __builtin_amdgcn_rcpf(1.0f + __expf(-x));
                partial += sig * We[d];
            }
            partial += __shfl_xor(partial, 1);
            partial += __shfl_xor(partial, 2);
            partial += __shfl_xor(partial, 4);
            partial += __shfl_xor(partial, 8);
            if (m == 0 && nv) ex_out[node] = __expf(partial);
        }
    }
}

// ---------------- binary search helper ----------------
__device__ __forceinline__ int lower_bound_dev(const int* __restrict__ seg, int N, int val) {
    int lo = 0, hi = N;
    while (lo < hi) {
        int mid = (lo + hi) >> 1;
        if (seg[mid] < val) lo = mid + 1; else hi = mid;
    }
    return lo;
}

// ---------------- K2: denom[b] = sum of ex over segment b ----------------
__global__ __launch_bounds__(256) void denom_kernel(const int* __restrict__ seg,
                                                    const float* __restrict__ ex,
                                                    float* __restrict__ denom, int N) {
    const int b = blockIdx.x, t = threadIdx.x;
    const int lo = lower_bound_dev(seg, N, b);
    const int hi = lower_bound_dev(seg, N, b + 1);
    float s = 0.f;
    for (int i = lo + t; i < hi; i += 256) s += ex[i];
    __shared__ float red[256];
    red[t] = s;
    __syncthreads();
    for (int off = 128; off > 0; off >>= 1) {
        if (t < off) red[t] += red[t + off];
        __syncthreads();
    }
    if (t == 0) denom[b] = red[0];
}

// ---------------- K3: rst[b] = sum_n (ex[n]/denom[b]) * feat_i[n] ----------------
// one 1024-thread block (16 waves) per segment; lane holds a float2 column pair; no atomics.
__global__ __launch_bounds__(1024) void out_kernel(const float* __restrict__ feat_i,
                                                   const int* __restrict__ seg,
                                                   const float* __restrict__ ex,
                                                   const float* __restrict__ denom,
                                                   float* __restrict__ out, int N) {
    const int b = blockIdx.x, t = threadIdx.x;
    const int wave = t >> 6, lane = t & 63;
    const int lo = lower_bound_dev(seg, N, b);
    const int hi = lower_bound_dev(seg, N, b + 1);
    const float inv = 1.0f / denom[b];  // unused if empty segment
    float2 acc = {0.f, 0.f};
    const float2* f2 = (const float2*)feat_i;
#pragma unroll 4
    for (int n = lo + wave; n < hi; n += 16) {
        const float w = ex[n] * inv;
        const float2 v = f2[(size_t)n * 64 + lane];
        acc.x += w * v.x;
        acc.y += w * v.y;
    }
    __shared__ float2 red[16][64];
    red[wave][lane] = acc;
    __syncthreads();
    if (wave == 0) {
#pragma unroll
        for (int ww = 1; ww < 16; ++ww) {
            acc.x += red[ww][lane].x;
            acc.y += red[ww][lane].y;
        }
        ((float2*)out)[b * 64 + lane] = acc;
    }
}

extern "C" void kernel_launch(void* const* d_in, const int* in_sizes, int n_in,
                              void* d_out, int out_size, void* d_ws, size_t ws_size,
                              hipStream_t stream) {
    const float* feat_i = (const float*)d_in[0];
    const float* feat_u = (const float*)d_in[1];
    const int*   seg    = (const int*)d_in[2];
    const float* W_key  = (const float*)d_in[3];
    const float* W_user = (const float*)d_in[4];
    const float* b_user = (const float*)d_in[5];
    const float* W_e    = (const float*)d_in[6];
    float* out = (float*)d_out;

    const int N = in_sizes[2];
    const int B = in_sizes[1] / DIM;

    // workspace layout
    char* ws = (char*)d_ws;
    float*          qry   = (float*)ws;                         // B*128*4   = 131072 B
    unsigned short* WkT   = (unsigned short*)(ws + 131072);     // 128*136*2 = 34816 B
    float*          denom = (float*)(ws + 131072 + 34816);      // B*4
    float*          ex    = (float*)(ws + 131072 + 34816 + 4096); // N*4

    qry_kernel<<<B, DIM, 0, stream>>>(feat_u, W_user, b_user, qry);
    wkt_kernel<<<(DIM * DIM) / 256, 256, 0, stream>>>(W_key, WkT);

    const int nblk = (N + 511) / 512;
    e_kernel<<<nblk, 256, 0, stream>>>(feat_i, seg, WkT, qry, W_e, ex, N);

    denom_kernel<<<B, 256, 0, stream>>>(seg, ex, denom, N);
    out_kernel<<<B, 1024, 0, stream>>>(feat_i, seg, ex, denom, out, N);
}